// Round 7
// baseline (377.373 us; speedup 1.0000x reference)
//
#include <hip/hip_runtime.h>
#include <hip/hip_bf16.h>
#include <stdint.h>

// ---------- types ----------
typedef _Float16 half8 __attribute__((ext_vector_type(8)));
typedef float floatx4 __attribute__((ext_vector_type(4)));

#define MFMA16(a, b, c) __builtin_amdgcn_mfma_f32_16x16x32_f16(a, b, c, 0, 0, 0)

// async global->LDS, 16B per lane, dest = wave-uniform base + lane*16
__device__ __forceinline__ void async_load16(const void* g, void* l) {
    __builtin_amdgcn_global_load_lds((__attribute__((address_space(1))) void*)(g),
                                     (__attribute__((address_space(3))) void*)(l),
                                     16, 0, 0);
}

#define RAW_BARRIER()  asm volatile("s_barrier" ::: "memory")
#define WAIT_VMCNT(n)  asm volatile("s_waitcnt vmcnt(" #n ")" ::: "memory")
#define WAIT_LGKM0()   asm volatile("s_waitcnt lgkmcnt(0)" ::: "memory")

// LDS XOR swizzle for [row][32]-fp16 panels (4 x 16B granules per 64B row):
//   stored slot p of row r holds global granule p ^ ((r>>1)&3)
//   reader at quad q reads slot q ^ ((r>>1)&3)  -> global granule q
// Staging lanes have r = base + (tid>>2), p = tid&3, so the pre-swizzled global
// granule is (tid&3) ^ ((tid>>3)&3) -- LDS dest stays linear (rule #21).

// ---------- fp32 -> fp16 conversion (with optional scale) ----------
__global__ __launch_bounds__(256) void cvt_kernel(const float* __restrict__ in,
                                                  _Float16* __restrict__ out,
                                                  int n, float scale) {
    int i = (blockIdx.x * 256 + threadIdx.x) * 8;
    if (i >= n) return;
    float4 v0 = *(const float4*)(in + i);
    float4 v1 = *(const float4*)(in + i + 4);
    half8 h;
    h[0] = (_Float16)(v0.x * scale);
    h[1] = (_Float16)(v0.y * scale);
    h[2] = (_Float16)(v0.z * scale);
    h[3] = (_Float16)(v0.w * scale);
    h[4] = (_Float16)(v1.x * scale);
    h[5] = (_Float16)(v1.y * scale);
    h[6] = (_Float16)(v1.z * scale);
    h[7] = (_Float16)(v1.w * scale);
    *(half8*)(out + i) = h;
}

// ---------- C[m][n] = sum_k A[m][k] * B[n][k] ----------
// 256x256 tile, BK=64, 8 waves, 8-phase schedule with COUNTED vmcnt (T3+T4):
// vmcnt(4) once per tile, never 0 in steady state; raw barriers; setprio
// around MFMA (T5); XCD remap + XOR swizzle. (Round-5, verified.)
__global__ __launch_bounds__(512, 2) void gemm_bt(const _Float16* __restrict__ A,
                                                  const _Float16* __restrict__ B,
                                                  _Float16* __restrict__ C,
                                                  int M, int N, int K) {
    __shared__ _Float16 sA[2][2][256 * 32];   // [buf][ksub][256 x 32] = 64 KB
    __shared__ _Float16 sB[2][2][256 * 32];   // 64 KB
    const int tid  = threadIdx.x;
    const int lane = tid & 63;
    const int w    = tid >> 6;
    const int quad = lane >> 4;
    const int m16  = lane & 15;
    const int mq   = (w >> 2) * 64;     // wave m quarter base within a 128-half
    const int nq   = (w & 3) * 32;      // wave n strip base within a 128-half

    // bijective XCD-chunk remap (total % 8 == 0), small grid dim fast.
    const int gx = gridDim.x, gy = gridDim.y;
    const int total = gx * gy;
    const int id = blockIdx.y * gx + blockIdx.x;
    const int logical = (id & 7) * (total >> 3) + (id >> 3);
    int bx, by;
    if (gx <= gy) { bx = logical % gx; by = logical / gx; }
    else          { by = logical % gy; bx = logical / gy; }
    const long row0 = (long)by * 256;
    const long col0 = (long)bx * 256;

    floatx4 acc[8][4] = {};

    const int swz = ((tid & 3) ^ ((tid >> 3) & 3)) * 8;   // pre-swizzled granule
    const _Float16* ga = A + (row0 + (tid >> 2)) * (long)K + swz;
    const _Float16* gb = B + (col0 + (tid >> 2)) * (long)K + swz;
    const int wchunk = w * 1024;        // wave-uniform byte base in a 128x32 panel

    auto stageA = [&](int tile, int half) {
        const int s = tile & 1;
        char* l0 = (char*)sA[s][0] + half * 8192 + wchunk;
        char* l1 = (char*)sA[s][1] + half * 8192 + wchunk;
        const _Float16* g = ga + (long)tile * 64 + (long)half * 128 * K;
        async_load16(g, l0);
        async_load16(g + 32, l1);
    };
    auto stageB = [&](int tile, int half) {
        const int s = tile & 1;
        char* l0 = (char*)sB[s][0] + half * 8192 + wchunk;
        char* l1 = (char*)sB[s][1] + half * 8192 + wchunk;
        const _Float16* g = gb + (long)tile * 64 + (long)half * 128 * K;
        async_load16(g, l0);
        async_load16(g + 32, l1);
    };

    const int rswz = (m16 >> 1) & 3;    // == (row>>1)&3 for row = base16 + m16
    const int NTt  = K >> 6;            // BK=64 tiles (16 for K=1024)

    // prologue: tile0 all 4 half-tiles + tile1 {A0,B0}  (12 loads/wave)
    stageA(0, 0); stageA(0, 1); stageB(0, 0); stageB(0, 1);
    stageA(1, 0); stageB(1, 0);
    WAIT_VMCNT(4);                      // tile0 resident; tile1 halves in flight
    RAW_BARRIER();

    for (int U = 0; U < NTt; ++U) {
        const int s = U & 1;
        const int T1 = U + 1, T2 = U + 2;
        half8 af[4][2], bf[2][2];
#pragma unroll
        for (int p = 0; p < 4; ++p) {
            const int mh = p >> 1, nh = p & 1;   // quadrant = (m-half, n-half)
            if ((p & 1) == 0) {                  // A frags reused across nh
#pragma unroll
                for (int mt = 0; mt < 4; mt++)
#pragma unroll
                    for (int j = 0; j < 2; j++)
                        af[mt][j] = *(const half8*)(sA[s][j] +
                            (mh * 128 + mq + mt * 16 + m16) * 32 + (quad ^ rswz) * 8);
            }
#pragma unroll
            for (int nt = 0; nt < 2; nt++)
#pragma unroll
                for (int j = 0; j < 2; j++)
                    bf[nt][j] = *(const half8*)(sB[s][j] +
                        (nh * 128 + nq + nt * 16 + m16) * 32 + (quad ^ rswz) * 8);
            // staging pattern (slot freed by preceding phase's last reader)
            if (p == 0 && T1 < NTt) stageB(T1, 1);
            if (p == 1 && T1 < NTt) stageA(T1, 1);
            if (p == 2 && T2 < NTt) stageA(T2, 0);
            if (p == 3 && T2 < NTt) stageB(T2, 0);
            if (p == 3) {
                if (T2 < NTt) { WAIT_VMCNT(4); }   // tile U+1 resident, U+2 in flight
                else          { WAIT_VMCNT(0); }   // tail drain
            }
            RAW_BARRIER();
            WAIT_LGKM0();
            __builtin_amdgcn_sched_barrier(0);
            __builtin_amdgcn_s_setprio(1);
#pragma unroll
            for (int mt = 0; mt < 4; mt++)
#pragma unroll
                for (int nt = 0; nt < 2; nt++) {
                    acc[mh * 4 + mt][nh * 2 + nt] =
                        MFMA16(af[mt][0], bf[nt][0], acc[mh * 4 + mt][nh * 2 + nt]);
                    acc[mh * 4 + mt][nh * 2 + nt] =
                        MFMA16(af[mt][1], bf[nt][1], acc[mh * 4 + mt][nh * 2 + nt]);
                }
            __builtin_amdgcn_s_setprio(0);
            RAW_BARRIER();
        }
    }

    // epilogue: frag MT>=4 lives in rows 128+, NT2>=2 in cols 128+
#pragma unroll
    for (int mt = 0; mt < 8; mt++)
#pragma unroll
        for (int nt = 0; nt < 4; nt++)
#pragma unroll
            for (int reg = 0; reg < 4; reg++) {
                long r = row0 + (mt >> 2) * 128 + mq + (mt & 3) * 16 + quad * 4 + reg;
                long c = col0 + (nt >> 1) * 128 + nq + (nt & 1) * 16 + m16;
                C[r * N + c] = (_Float16)acc[mt][nt][reg];
            }
}

// ---------- attention kernel A: banded S = Q K^T -> softmax -> P (fp16) ----------
// block = 64 q-rows, 512 threads / 8 waves. COUNTED-vmcnt 2-deep pipeline (T4):
// staging fixed at 36 K-tiles for ALL blocks (uniform per-wave load counts:
// w<4: 5K+1Q=6, w>=4: 4K). Padded tiles (t >= ntReal) read workspace garbage;
// the mask kills them UNCONDITIONALLY (Round-6 bug: for tail blocks where
// kend==S, padded j in [S, kstart+576) can satisfy |qi-j|<=256 -- the band
// test alone does NOT cover them. Must OR with t >= ntReal). Per D-step:
// {vmcnt(6/4) [tile k landed, k+1 in flight] -> s_barrier -> ds_read+MFMA ->
//  lgkmcnt(0) -> s_barrier -> stage tile k+2}. vmcnt never 0 until the tail.
__global__ __launch_bounds__(512) void qk_kernel(const _Float16* __restrict__ Qh,
                                                 const _Float16* __restrict__ Kh,
                                                 _Float16* __restrict__ Pg,
                                                 float* __restrict__ invSum) {
    const int S = 4096, D = 1024;
    __shared__ _Float16 sK[2][576 * 32];   // 2 x 36 KB (36 tiles, fixed)
    __shared__ _Float16 sQ[2][64 * 32];    // 2 x 4 KB
    __shared__ float sMax[64][8];
    __shared__ float sSum[64][8];

    const int tid  = threadIdx.x;
    const int lane = tid & 63;
    const int w    = tid >> 6;
    const int quad = lane >> 4;
    const int c16  = lane & 15;
    // bijective XCD-chunk remap (256 % 8 == 0)
    const int qblk = (blockIdx.x & 7) * 32 + (blockIdx.x >> 3);
    const int b    = qblk >> 6;
    const int q0   = (qblk & 63) << 6;

    int kstart = q0 - 256; if (kstart < 0) kstart = 0;   // multiple of 64
    int kend   = q0 + 320; if (kend > S) kend = S;       // multiple of 64
    const int ntReal = (kend - kstart) >> 4;             // real tiles (20..36)

    const int lrow = lane >> 2;                          // 0..15
    const int swz  = ((lane & 3) ^ ((lane >> 3) & 3)) * 8;  // pre-swizzled granule
    const _Float16* Kbase = Kh + ((long)(b * S + kstart) + lrow) * D + swz;
    const _Float16* Qbase = Qh + ((long)(b * S + q0) + w * 16 + lrow) * D + swz;

    // fixed 36-tile staging; overrun rows land inside the workspace (masked).
    auto stage = [&](int bi, int kc) {
#pragma unroll
        for (int j = 0; j < 5; j++) {
            if (j < 4 || w < 4) {                    // g = j*8+w < 36
                int g = j * 8 + w;
                async_load16(Kbase + (long)g * 16 * D + kc, (char*)sK[bi] + g * 1024);
            }
        }
        if (w < 4)
            async_load16(Qbase + kc, (char*)sQ[bi] + w * 1024);
    };

    const int rswz = ((c16 >> 1) & 3);   // == (row>>1)&3 for row = 16*base + c16

    floatx4 acc[4][5] = {};
    stage(0, 0);
    stage(1, 32);
    for (int kc = 0; kc < 1024; kc += 32) {
        const int bi = (kc >> 5) & 1;
        if (kc + 32 < 1024) {            // tile kc landed; tile kc+32 in flight
            if (w < 4) { WAIT_VMCNT(6); } else { WAIT_VMCNT(4); }
        } else {
            WAIT_VMCNT(0);               // tail drain
        }
        RAW_BARRIER();
        half8 aQ[4];
#pragma unroll
        for (int mt = 0; mt < 4; mt++)
            aQ[mt] = *(const half8*)(sQ[bi] + (mt * 16 + c16) * 32 + (quad ^ rswz) * 8);
#pragma unroll
        for (int i = 0; i < 5; i++) {
            if (i < 4 || w < 4) {                    // t = w + i*8 < 36
                int t = w + i * 8;
                half8 bK = *(const half8*)(sK[bi] + (t * 16 + c16) * 32 + (quad ^ rswz) * 8);
#pragma unroll
                for (int mt = 0; mt < 4; mt++)
                    acc[mt][i] = MFMA16(aQ[mt], bK, acc[mt][i]);
            }
        }
        WAIT_LGKM0();                    // this wave's LDS reads landed
        RAW_BARRIER();                   // all waves done with buf bi
        if (kc + 64 < 1024) stage(bi, kc + 64);
    }

    // band mask. MUST also unconditionally kill padded tiles (t >= ntReal):
    // for tail blocks kend==S, padded j can sit within the +-256 band.
#pragma unroll
    for (int i = 0; i < 5; i++) {
        if (i < 4 || w < 4) {
            int t = w + i * 8;
            int j = kstart + t * 16 + c16;
            bool pad = (t >= ntReal);                // wave-uniform per i
#pragma unroll
            for (int mt = 0; mt < 4; mt++)
#pragma unroll
                for (int r = 0; r < 4; r++) {
                    int qi = q0 + mt * 16 + quad * 4 + r;
                    int dd = qi - j; dd = dd < 0 ? -dd : dd;
                    if (dd > 256 || pad) acc[mt][i][r] = -1e30f;
                }
        }
    }
    // partial row max (this wave's band-eighth), reduce over the 16-lane col group
#pragma unroll
    for (int mt = 0; mt < 4; mt++)
#pragma unroll
        for (int r = 0; r < 4; r++) {
            float m = -1e30f;
#pragma unroll
            for (int i = 0; i < 5; i++)
                if (i < 4 || w < 4) m = fmaxf(m, acc[mt][i][r]);
#pragma unroll
            for (int off = 1; off < 16; off <<= 1) m = fmaxf(m, __shfl_xor(m, off, 64));
            if (c16 == 0) sMax[mt * 16 + quad * 4 + r][w] = m;
        }
    __syncthreads();
    if (tid < 64) {
        float fm = sMax[tid][0];
#pragma unroll
        for (int j = 1; j < 8; j++) fm = fmaxf(fm, sMax[tid][j]);
        sMax[tid][0] = fm;
    }
    __syncthreads();
    // exp, write P (guarded by REAL tiles), partial sums (padded e = 0)
#pragma unroll
    for (int mt = 0; mt < 4; mt++)
#pragma unroll
        for (int r = 0; r < 4; r++) {
            int row = mt * 16 + quad * 4 + r;
            float fm = sMax[row][0];
            float s = 0.f;
#pragma unroll
            for (int i = 0; i < 5; i++) {
                if (i < 4 || w < 4) {
                    int t = w + i * 8;
                    float e = __expf(acc[mt][i][r] - fm);   // masked -> 0
                    s += e;
                    if (t < ntReal)
                        Pg[(long)qblk * 36864 + row * 576 + t * 16 + c16] = (_Float16)e;
                }
            }
#pragma unroll
            for (int off = 1; off < 16; off <<= 1) s += __shfl_xor(s, off, 64);
            if (c16 == 0) sSum[row][w] = s;
        }
    __syncthreads();
    if (tid < 64) {
        float t = 0.f;
#pragma unroll
        for (int j = 0; j < 8; j++) t += sSum[tid][j];
        invSum[qblk * 64 + tid] = 1.f / t;
    }
}

// ---------- attention kernel B: O = P V (banded), from Vt [d][tok] ----------
// COUNTED-vmcnt 2-deep pipeline (T4) on the proven LDS-staged structure:
// per step {vmcnt(3/2) -> barrier -> ds_read+MFMA -> lgkmcnt(0) -> barrier ->
// stage step+2}. All staged tiles are REAL (nsteps exact), no padding hazard.
// XCD-chunked remap + XOR-swizzled LDS retained.
__global__ __launch_bounds__(512) void pv_kernel(const _Float16* __restrict__ Pg,
                                                 const float* __restrict__ invSum,
                                                 const _Float16* __restrict__ Vt,
                                                 float* __restrict__ out) {
    const int S = 4096, D = 1024, TOK = 16384;
    __shared__ _Float16 sA[2][64 * 32];    // 2 x 4 KB
    __shared__ _Float16 sB[2][256 * 32];   // 2 x 16 KB

    const int tid  = threadIdx.x;
    const int lane = tid & 63;
    const int w    = tid >> 6;
    const int quad = lane >> 4;
    const int c16  = lane & 15;

    // bijective XCD-chunk remap (1024 % 8 == 0); n-block inner, qblk outer
    const int logical = (blockIdx.x & 7) * 128 + (blockIdx.x >> 3);
    const int qblk = logical >> 2;      // qblk/32 == XCD id, matches qk_kernel
    const int n0   = (logical & 3) << 8;
    const int b    = qblk >> 6;
    const int q0   = (qblk & 63) << 6;

    int kstart = q0 - 256; if (kstart < 0) kstart = 0;
    int kend   = q0 + 320; if (kend > S) kend = S;
    const int nsteps = (kend - kstart) >> 5;   // 10..18, even

    const int lrow = lane >> 2;
    const int swz  = ((lane & 3) ^ ((lane >> 3) & 3)) * 8;  // pre-swizzled granule
    const _Float16* Abase = Pg + (long)qblk * 36864 + (w * 16 + lrow) * 576 + swz;
    const _Float16* Bbase = Vt + (long)(n0 + lrow) * TOK + b * S + kstart + swz;

    auto stage = [&](int bi, int kc) {
        if (w < 4)
            async_load16(Abase + kc, (char*)sA[bi] + w * 1024);
#pragma unroll
        for (int j = 0; j < 2; j++) {
            int g = j * 8 + w;
            async_load16(Bbase + (long)g * 16 * TOK + kc, (char*)sB[bi] + g * 1024);
        }
    };

    const int wm = (w >> 2) * 32;
    const int wn = (w & 3) * 64;
    const int rswz = ((c16 >> 1) & 3);   // == (row>>1)&3 for row = 16*base + c16
    floatx4 acc[2][4] = {};

    stage(0, 0);
    stage(1, 32);
    for (int s = 0; s < nsteps; s++) {
        const int bi = s & 1;
        if (s + 1 < nsteps) {            // tile s landed; tile s+1 in flight
            if (w < 4) { WAIT_VMCNT(3); } else { WAIT_VMCNT(2); }
        } else {
            WAIT_VMCNT(0);               // tail drain
        }
        RAW_BARRIER();
        half8 aA[2], bB[4];
#pragma unroll
        for (int mt = 0; mt < 2; mt++)
            aA[mt] = *(const half8*)(sA[bi] + (wm + mt * 16 + c16) * 32 + (quad ^ rswz) * 8);
#pragma unroll
        for (int nt = 0; nt < 4; nt++)
            bB[nt] = *(const half8*)(sB[bi] + (wn + nt * 16 + c16) * 32 + (quad ^ rswz) * 8);
#pragma unroll
        for (int mt = 0; mt < 2; mt++)
#pragma unroll
            for (int nt = 0; nt < 4; nt++)
                acc[mt][nt] = MFMA16(aA[mt], bB[nt], acc[mt][nt]);
        WAIT_LGKM0();                    // this wave's LDS reads landed
        RAW_BARRIER();                   // all waves done with buf bi
        if (s + 2 < nsteps) stage(bi, (s + 2) * 32);
    }

    const float* isB = invSum + qblk * 64;
#pragma unroll
    for (int mt = 0; mt < 2; mt++)
#pragma unroll
        for (int nt = 0; nt < 4; nt++)
#pragma unroll
            for (int reg = 0; reg < 4; reg++) {
                int row = wm + mt * 16 + quad * 4 + reg;
                int col = n0 + wn + nt * 16 + c16;
                out[(long)(b * S + q0 + row) * D + col] = acc[mt][nt][reg] * isB[row];
            }
}

extern "C" void kernel_launch(void* const* d_in, const int* in_sizes, int n_in,
                              void* d_out, int out_size, void* d_ws, size_t ws_size,
                              hipStream_t stream) {
    const float* X  = (const float*)d_in[0];
    const float* Y  = (const float*)d_in[1];
    const float* Wq = (const float*)d_in[2];
    const float* Wk = (const float*)d_in[3];
    const float* Wv = (const float*)d_in[4];
    float* out = (float*)d_out;

    const long NTOK = 16384, D = 1024;
    // fp16 workspace. Aliases (all stream-ordered safe):
    //   Kh = Yh   (Yh dead after Q-projection)
    //   Pg,invSum over Xh (Xh dead after V-projection; qk_kernel runs after)
    char* p = (char*)d_ws;
    _Float16* Xh  = (_Float16*)p; p += NTOK * D * 2;   // 32 MB
    _Float16* Yh  = (_Float16*)p; p += NTOK * D * 2;   // 32 MB (reused as Kh)
    _Float16* Wqh = (_Float16*)p; p += D * D * 2;      //  2 MB (pre-scaled by 1/32)
    _Float16* Wkh = (_Float16*)p; p += D * D * 2;
    _Float16* Wvh = (_Float16*)p; p += D * D * 2;
    _Float16* Qh  = (_Float16*)p; p += NTOK * D * 2;   // 32 MB
    _Float16* Vt  = (_Float16*)p; p += NTOK * D * 2;   // 32 MB  [D][NTOK]
    _Float16* Kh  = Yh;
    _Float16* Pg  = Xh;                                // 256*64*576*2 = 18.9 MB
    float* invSum = (float*)(Xh + 256l * 64 * 576);    // 64 KB, still inside Xh

    const int nT = (int)(NTOK * D);
    const int nW = (int)(D * D);
    cvt_kernel<<<nT / 2048, 256, 0, stream>>>(X, Xh, nT, 1.f);
    cvt_kernel<<<nT / 2048, 256, 0, stream>>>(Y, Yh, nT, 1.f);
    cvt_kernel<<<nW / 2048, 256, 0, stream>>>(Wq, Wqh, nW, 0.03125f);  // fold 1/sqrt(1024)
    cvt_kernel<<<nW / 2048, 256, 0, stream>>>(Wk, Wkh, nW, 1.f);
    cvt_kernel<<<nW / 2048, 256, 0, stream>>>(Wv, Wvh, nW, 1.f);

    // Q = Y Wq^T (scaled), K = X Wk^T, Vt = Wv X^T  (256^2 tiles, 8-phase)
    gemm_bt<<<dim3(1024 / 256, 16384 / 256), 512, 0, stream>>>(Yh, Wqh, Qh, 16384, 1024, 1024);
    gemm_bt<<<dim3(1024 / 256, 16384 / 256), 512, 0, stream>>>(Xh, Wkh, Kh, 16384, 1024, 1024);
    gemm_bt<<<dim3(16384 / 256, 1024 / 256), 512, 0, stream>>>(Wvh, Xh, Vt, 1024, 16384, 1024);

    qk_kernel<<<dim3(256), 512, 0, stream>>>(Qh, Kh, Pg, invSum);
    pv_kernel<<<dim3(4 * 256), 512, 0, stream>>>(Pg, invSum, Vt, out);
}

// Round 9
// 369.970 us; speedup vs baseline: 1.0200x; 1.0200x over previous
//
#include <hip/hip_runtime.h>
#include <hip/hip_bf16.h>
#include <stdint.h>

// ---------- types ----------
typedef _Float16 half8 __attribute__((ext_vector_type(8)));
typedef float floatx4 __attribute__((ext_vector_type(4)));

#define MFMA16(a, b, c) __builtin_amdgcn_mfma_f32_16x16x32_f16(a, b, c, 0, 0, 0)

// async global->LDS, 16B per lane, dest = wave-uniform base + lane*16
__device__ __forceinline__ void async_load16(const void* g, void* l) {
    __builtin_amdgcn_global_load_lds((__attribute__((address_space(1))) void*)(g),
                                     (__attribute__((address_space(3))) void*)(l),
                                     16, 0, 0);
}

#define RAW_BARRIER()  asm volatile("s_barrier" ::: "memory")
#define WAIT_VMCNT(n)  asm volatile("s_waitcnt vmcnt(" #n ")" ::: "memory")
#define WAIT_LGKM0()   asm volatile("s_waitcnt lgkmcnt(0)" ::: "memory")

// LDS XOR swizzle for [row][32]-fp16 panels (4 x 16B granules per 64B row):
//   stored slot p of row r holds global granule p ^ ((r>>1)&3)
//   reader at quad q reads slot q ^ ((r>>1)&3)  -> global granule q
// Staging lanes have r = base + (tid>>2), p = tid&3, so the pre-swizzled global
// granule is (tid&3) ^ ((tid>>3)&3) -- LDS dest stays linear (rule #21).

// ---------- fp32 -> fp16 conversion, two tensors in one launch ----------
__global__ __launch_bounds__(256) void cvt2_kernel(const float* __restrict__ in0,
                                                   _Float16* __restrict__ out0, int n0,
                                                   const float* __restrict__ in1,
                                                   _Float16* __restrict__ out1) {
    long i = ((long)blockIdx.x * 256 + threadIdx.x) * 8;
    const float* in; _Float16* out;
    if (i < n0) { in = in0 + i; out = out0 + i; }
    else        { in = in1 + (i - n0); out = out1 + (i - n0); }
    float4 v0 = *(const float4*)(in);
    float4 v1 = *(const float4*)(in + 4);
    half8 h;
    h[0] = (_Float16)v0.x; h[1] = (_Float16)v0.y;
    h[2] = (_Float16)v0.z; h[3] = (_Float16)v0.w;
    h[4] = (_Float16)v1.x; h[5] = (_Float16)v1.y;
    h[6] = (_Float16)v1.z; h[7] = (_Float16)v1.w;
    *(half8*)(out) = h;
}

// ---------- fp32 -> fp16 for the three DxD weights (Wq pre-scaled) ----------
__global__ __launch_bounds__(256) void cvt3w_kernel(const float* __restrict__ wq,
                                                    const float* __restrict__ wk,
                                                    const float* __restrict__ wv,
                                                    _Float16* __restrict__ oq,
                                                    _Float16* __restrict__ ok,
                                                    _Float16* __restrict__ ov) {
    const int nW8 = (1024 * 1024) / 8;
    int idx = blockIdx.x * 256 + threadIdx.x;
    int seg = idx / nW8;
    long i = (long)(idx - seg * nW8) * 8;
    const float* in = (seg == 0) ? wq : (seg == 1) ? wk : wv;
    _Float16* out   = (seg == 0) ? oq : (seg == 1) ? ok : ov;
    float scale = (seg == 0) ? 0.03125f : 1.f;   // fold 1/sqrt(1024) into Wq
    float4 v0 = *(const float4*)(in + i);
    float4 v1 = *(const float4*)(in + i + 4);
    half8 h;
    h[0] = (_Float16)(v0.x * scale); h[1] = (_Float16)(v0.y * scale);
    h[2] = (_Float16)(v0.z * scale); h[3] = (_Float16)(v0.w * scale);
    h[4] = (_Float16)(v1.x * scale); h[5] = (_Float16)(v1.y * scale);
    h[6] = (_Float16)(v1.z * scale); h[7] = (_Float16)(v1.w * scale);
    *(half8*)(out + i) = h;
}

// ---------- C[m][n] = sum_k A[m][k] * B[n][k] ----------
// 256x256 tile, BK=64, 8 waves, 8-phase schedule with COUNTED vmcnt (T3+T4):
// vmcnt(4) once per tile, never 0 in steady state; raw barriers; setprio
// around MFMA (T5); XCD remap + XOR swizzle. (Round-5, verified.)
__global__ __launch_bounds__(512, 2) void gemm_bt(const _Float16* __restrict__ A,
                                                  const _Float16* __restrict__ B,
                                                  _Float16* __restrict__ C,
                                                  int M, int N, int K) {
    __shared__ _Float16 sA[2][2][256 * 32];   // [buf][ksub][256 x 32] = 64 KB
    __shared__ _Float16 sB[2][2][256 * 32];   // 64 KB
    const int tid  = threadIdx.x;
    const int lane = tid & 63;
    const int w    = tid >> 6;
    const int quad = lane >> 4;
    const int m16  = lane & 15;
    const int mq   = (w >> 2) * 64;     // wave m quarter base within a 128-half
    const int nq   = (w & 3) * 32;      // wave n strip base within a 128-half

    // bijective XCD-chunk remap (total % 8 == 0), small grid dim fast.
    const int gx = gridDim.x, gy = gridDim.y;
    const int total = gx * gy;
    const int id = blockIdx.y * gx + blockIdx.x;
    const int logical = (id & 7) * (total >> 3) + (id >> 3);
    int bx, by;
    if (gx <= gy) { bx = logical % gx; by = logical / gx; }
    else          { by = logical % gy; bx = logical / gy; }
    const long row0 = (long)by * 256;
    const long col0 = (long)bx * 256;

    floatx4 acc[8][4] = {};

    const int swz = ((tid & 3) ^ ((tid >> 3) & 3)) * 8;   // pre-swizzled granule
    const _Float16* ga = A + (row0 + (tid >> 2)) * (long)K + swz;
    const _Float16* gb = B + (col0 + (tid >> 2)) * (long)K + swz;
    const int wchunk = w * 1024;        // wave-uniform byte base in a 128x32 panel

    auto stageA = [&](int tile, int half) {
        const int s = tile & 1;
        char* l0 = (char*)sA[s][0] + half * 8192 + wchunk;
        char* l1 = (char*)sA[s][1] + half * 8192 + wchunk;
        const _Float16* g = ga + (long)tile * 64 + (long)half * 128 * K;
        async_load16(g, l0);
        async_load16(g + 32, l1);
    };
    auto stageB = [&](int tile, int half) {
        const int s = tile & 1;
        char* l0 = (char*)sB[s][0] + half * 8192 + wchunk;
        char* l1 = (char*)sB[s][1] + half * 8192 + wchunk;
        const _Float16* g = gb + (long)tile * 64 + (long)half * 128 * K;
        async_load16(g, l0);
        async_load16(g + 32, l1);
    };

    const int rswz = (m16 >> 1) & 3;    // == (row>>1)&3 for row = base16 + m16
    const int NTt  = K >> 6;            // BK=64 tiles (16 for K=1024)

    // prologue: tile0 all 4 half-tiles + tile1 {A0,B0}  (12 loads/wave)
    stageA(0, 0); stageA(0, 1); stageB(0, 0); stageB(0, 1);
    stageA(1, 0); stageB(1, 0);
    WAIT_VMCNT(4);                      // tile0 resident; tile1 halves in flight
    RAW_BARRIER();

    for (int U = 0; U < NTt; ++U) {
        const int s = U & 1;
        const int T1 = U + 1, T2 = U + 2;
        half8 af[4][2], bf[2][2];
#pragma unroll
        for (int p = 0; p < 4; ++p) {
            const int mh = p >> 1, nh = p & 1;   // quadrant = (m-half, n-half)
            if ((p & 1) == 0) {                  // A frags reused across nh
#pragma unroll
                for (int mt = 0; mt < 4; mt++)
#pragma unroll
                    for (int j = 0; j < 2; j++)
                        af[mt][j] = *(const half8*)(sA[s][j] +
                            (mh * 128 + mq + mt * 16 + m16) * 32 + (quad ^ rswz) * 8);
            }
#pragma unroll
            for (int nt = 0; nt < 2; nt++)
#pragma unroll
                for (int j = 0; j < 2; j++)
                    bf[nt][j] = *(const half8*)(sB[s][j] +
                        (nh * 128 + nq + nt * 16 + m16) * 32 + (quad ^ rswz) * 8);
            // staging pattern (slot freed by preceding phase's last reader)
            if (p == 0 && T1 < NTt) stageB(T1, 1);
            if (p == 1 && T1 < NTt) stageA(T1, 1);
            if (p == 2 && T2 < NTt) stageA(T2, 0);
            if (p == 3 && T2 < NTt) stageB(T2, 0);
            if (p == 3) {
                if (T2 < NTt) { WAIT_VMCNT(4); }   // tile U+1 resident, U+2 in flight
                else          { WAIT_VMCNT(0); }   // tail drain
            }
            RAW_BARRIER();
            WAIT_LGKM0();
            __builtin_amdgcn_sched_barrier(0);
            __builtin_amdgcn_s_setprio(1);
#pragma unroll
            for (int mt = 0; mt < 4; mt++)
#pragma unroll
                for (int nt = 0; nt < 2; nt++) {
                    acc[mh * 4 + mt][nh * 2 + nt] =
                        MFMA16(af[mt][0], bf[nt][0], acc[mh * 4 + mt][nh * 2 + nt]);
                    acc[mh * 4 + mt][nh * 2 + nt] =
                        MFMA16(af[mt][1], bf[nt][1], acc[mh * 4 + mt][nh * 2 + nt]);
                }
            __builtin_amdgcn_s_setprio(0);
            RAW_BARRIER();
        }
    }

    // epilogue: frag MT>=4 lives in rows 128+, NT2>=2 in cols 128+
#pragma unroll
    for (int mt = 0; mt < 8; mt++)
#pragma unroll
        for (int nt = 0; nt < 4; nt++)
#pragma unroll
            for (int reg = 0; reg < 4; reg++) {
                long r = row0 + (mt >> 2) * 128 + mq + (mt & 3) * 16 + quad * 4 + reg;
                long c = col0 + (nt >> 1) * 128 + nq + (nt & 1) * 16 + m16;
                C[r * N + c] = (_Float16)acc[mt][nt][reg];
            }
}

// ---------- attention kernel A: banded S = Q K^T -> softmax -> P (fp16) ----------
// block = 64 q-rows, 512 threads / 8 waves. TRIPLE-buffered counted-vmcnt
// pipeline (lookahead 3 steps, 2 stages always in flight): per D-step the
// block's barrier join waits on the slowest of 40 staged loads -- deeper
// lookahead moves the wait target from "issued 2 steps ago" to "3 steps ago",
// hiding the L3-miss/queueing tail. LDS 3x(36+4)KB + 4KB = 124 KB (still 1
// block/CU). Staging fixed at 36 K-tiles (uniform per-wave counts: w<4 6,
// w>=4 4); padded tiles killed UNCONDITIONALLY by the mask (t >= ntReal --
// Round-6 lesson: band test alone misses tail-block padding).
__global__ __launch_bounds__(512) void qk_kernel(const _Float16* __restrict__ Qh,
                                                 const _Float16* __restrict__ Kh,
                                                 _Float16* __restrict__ Pg,
                                                 float* __restrict__ invSum) {
    const int S = 4096, D = 1024;
    __shared__ _Float16 sK[3][576 * 32];   // 3 x 36 KB
    __shared__ _Float16 sQ[3][64 * 32];    // 3 x 4 KB
    __shared__ float sMax[64][8];
    __shared__ float sSum[64][8];

    const int tid  = threadIdx.x;
    const int lane = tid & 63;
    const int w    = tid >> 6;
    const int quad = lane >> 4;
    const int c16  = lane & 15;
    // bijective XCD-chunk remap (256 % 8 == 0)
    const int qblk = (blockIdx.x & 7) * 32 + (blockIdx.x >> 3);
    const int b    = qblk >> 6;
    const int q0   = (qblk & 63) << 6;

    int kstart = q0 - 256; if (kstart < 0) kstart = 0;   // multiple of 64
    int kend   = q0 + 320; if (kend > S) kend = S;       // multiple of 64
    const int ntReal = (kend - kstart) >> 4;             // real tiles (20..36)

    const int lrow = lane >> 2;                          // 0..15
    const int swz  = ((lane & 3) ^ ((lane >> 3) & 3)) * 8;  // pre-swizzled granule
    const _Float16* Kbase = Kh + ((long)(b * S + kstart) + lrow) * D + swz;
    const _Float16* Qbase = Qh + ((long)(b * S + q0) + w * 16 + lrow) * D + swz;

    // fixed 36-tile staging; overrun rows land inside the workspace (masked).
    auto stage = [&](int bi, int kc) {
#pragma unroll
        for (int j = 0; j < 5; j++) {
            if (j < 4 || w < 4) {                    // g = j*8+w < 36
                int g = j * 8 + w;
                async_load16(Kbase + (long)g * 16 * D + kc, (char*)sK[bi] + g * 1024);
            }
        }
        if (w < 4)
            async_load16(Qbase + kc, (char*)sQ[bi] + w * 1024);
    };

    const int rswz = ((c16 >> 1) & 3);   // == (row>>1)&3 for row = 16*base + c16

    floatx4 acc[4][5] = {};
    stage(0, 0);
    stage(1, 32);
    stage(2, 64);
    for (int kc = 0; kc < 1024; kc += 32) {
        const int st = kc >> 5;
        const int bi = st % 3;
        if (st <= 29) {                  // stages st+1, st+2 in flight
            if (w < 4) { WAIT_VMCNT(12); } else { WAIT_VMCNT(8); }
        } else if (st == 30) {           // only stage 31 in flight
            if (w < 4) { WAIT_VMCNT(6); } else { WAIT_VMCNT(4); }
        } else {
            WAIT_VMCNT(0);               // tail drain
        }
        RAW_BARRIER();
        half8 aQ[4];
#pragma unroll
        for (int mt = 0; mt < 4; mt++)
            aQ[mt] = *(const half8*)(sQ[bi] + (mt * 16 + c16) * 32 + (quad ^ rswz) * 8);
#pragma unroll
        for (int i = 0; i < 5; i++) {
            if (i < 4 || w < 4) {                    // t = w + i*8 < 36
                int t = w + i * 8;
                half8 bK = *(const half8*)(sK[bi] + (t * 16 + c16) * 32 + (quad ^ rswz) * 8);
#pragma unroll
                for (int mt = 0; mt < 4; mt++)
                    acc[mt][i] = MFMA16(aQ[mt], bK, acc[mt][i]);
            }
        }
        WAIT_LGKM0();                    // this wave's LDS reads landed
        RAW_BARRIER();                   // all waves done with buf bi
        if (st + 3 <= 31) stage(bi, kc + 96);
    }

    // band mask. MUST also unconditionally kill padded tiles (t >= ntReal):
    // for tail blocks kend==S, padded j can sit within the +-256 band.
#pragma unroll
    for (int i = 0; i < 5; i++) {
        if (i < 4 || w < 4) {
            int t = w + i * 8;
            int j = kstart + t * 16 + c16;
            bool pad = (t >= ntReal);                // wave-uniform per i
#pragma unroll
            for (int mt = 0; mt < 4; mt++)
#pragma unroll
                for (int r = 0; r < 4; r++) {
                    int qi = q0 + mt * 16 + quad * 4 + r;
                    int dd = qi - j; dd = dd < 0 ? -dd : dd;
                    if (dd > 256 || pad) acc[mt][i][r] = -1e30f;
                }
        }
    }
    // partial row max (this wave's band-eighth), reduce over the 16-lane col group
#pragma unroll
    for (int mt = 0; mt < 4; mt++)
#pragma unroll
        for (int r = 0; r < 4; r++) {
            float m = -1e30f;
#pragma unroll
            for (int i = 0; i < 5; i++)
                if (i < 4 || w < 4) m = fmaxf(m, acc[mt][i][r]);
#pragma unroll
            for (int off = 1; off < 16; off <<= 1) m = fmaxf(m, __shfl_xor(m, off, 64));
            if (c16 == 0) sMax[mt * 16 + quad * 4 + r][w] = m;
        }
    __syncthreads();
    if (tid < 64) {
        float fm = sMax[tid][0];
#pragma unroll
        for (int j = 1; j < 8; j++) fm = fmaxf(fm, sMax[tid][j]);
        sMax[tid][0] = fm;
    }
    __syncthreads();
    // exp, write P (guarded by REAL tiles), partial sums (padded e = 0)
#pragma unroll
    for (int mt = 0; mt < 4; mt++)
#pragma unroll
        for (int r = 0; r < 4; r++) {
            int row = mt * 16 + quad * 4 + r;
            float fm = sMax[row][0];
            float s = 0.f;
#pragma unroll
            for (int i = 0; i < 5; i++) {
                if (i < 4 || w < 4) {
                    int t = w + i * 8;
                    float e = __expf(acc[mt][i][r] - fm);   // masked -> 0
                    s += e;
                    if (t < ntReal)
                        Pg[(long)qblk * 36864 + row * 576 + t * 16 + c16] = (_Float16)e;
                }
            }
#pragma unroll
            for (int off = 1; off < 16; off <<= 1) s += __shfl_xor(s, off, 64);
            if (c16 == 0) sSum[row][w] = s;
        }
    __syncthreads();
    if (tid < 64) {
        float t = 0.f;
#pragma unroll
        for (int j = 0; j < 8; j++) t += sSum[tid][j];
        invSum[qblk * 64 + tid] = 1.f / t;
    }
}

// ---------- attention kernel B: O = P V (banded), from Vt [d][tok] ----------
// COUNTED-vmcnt 2-deep pipeline (T4) on the proven LDS-staged structure:
// per step {vmcnt(3/2) -> barrier -> ds_read+MFMA -> lgkmcnt(0) -> barrier ->
// stage step+2}. All staged tiles are REAL (nsteps exact), no padding hazard.
// XCD-chunked remap + XOR-swizzled LDS retained. (Round-7, verified.)
__global__ __launch_bounds__(512) void pv_kernel(const _Float16* __restrict__ Pg,
                                                 const float* __restrict__ invSum,
                                                 const _Float16* __restrict__ Vt,
                                                 float* __restrict__ out) {
    const int S = 4096, D = 1024, TOK = 16384;
    __shared__ _Float16 sA[2][64 * 32];    // 2 x 4 KB
    __shared__ _Float16 sB[2][256 * 32];   // 2 x 16 KB

    const int tid  = threadIdx.x;
    const int lane = tid & 63;
    const int w    = tid >> 6;
    const int quad = lane >> 4;
    const int c16  = lane & 15;

    // bijective XCD-chunk remap (1024 % 8 == 0); n-block inner, qblk outer
    const int logical = (blockIdx.x & 7) * 128 + (blockIdx.x >> 3);
    const int qblk = logical >> 2;      // qblk/32 == XCD id, matches qk_kernel
    const int n0   = (logical & 3) << 8;
    const int b    = qblk >> 6;
    const int q0   = (qblk & 63) << 6;

    int kstart = q0 - 256; if (kstart < 0) kstart = 0;
    int kend   = q0 + 320; if (kend > S) kend = S;
    const int nsteps = (kend - kstart) >> 5;   // 10..18, even

    const int lrow = lane >> 2;
    const int swz  = ((lane & 3) ^ ((lane >> 3) & 3)) * 8;  // pre-swizzled granule
    const _Float16* Abase = Pg + (long)qblk * 36864 + (w * 16 + lrow) * 576 + swz;
    const _Float16* Bbase = Vt + (long)(n0 + lrow) * TOK + b * S + kstart + swz;

    auto stage = [&](int bi, int kc) {
        if (w < 4)
            async_load16(Abase + kc, (char*)sA[bi] + w * 1024);
#pragma unroll
        for (int j = 0; j < 2; j++) {
            int g = j * 8 + w;
            async_load16(Bbase + (long)g * 16 * TOK + kc, (char*)sB[bi] + g * 1024);
        }
    };

    const int wm = (w >> 2) * 32;
    const int wn = (w & 3) * 64;
    const int rswz = ((c16 >> 1) & 3);   // == (row>>1)&3 for row = 16*base + c16
    floatx4 acc[2][4] = {};

    stage(0, 0);
    stage(1, 32);
    for (int s = 0; s < nsteps; s++) {
        const int bi = s & 1;
        if (s + 1 < nsteps) {            // tile s landed; tile s+1 in flight
            if (w < 4) { WAIT_VMCNT(3); } else { WAIT_VMCNT(2); }
        } else {
            WAIT_VMCNT(0);               // tail drain
        }
        RAW_BARRIER();
        half8 aA[2], bB[4];
#pragma unroll
        for (int mt = 0; mt < 2; mt++)
            aA[mt] = *(const half8*)(sA[bi] + (wm + mt * 16 + c16) * 32 + (quad ^ rswz) * 8);
#pragma unroll
        for (int nt = 0; nt < 4; nt++)
            bB[nt] = *(const half8*)(sB[bi] + (wn + nt * 16 + c16) * 32 + (quad ^ rswz) * 8);
#pragma unroll
        for (int mt = 0; mt < 2; mt++)
#pragma unroll
            for (int nt = 0; nt < 4; nt++)
                acc[mt][nt] = MFMA16(aA[mt], bB[nt], acc[mt][nt]);
        WAIT_LGKM0();                    // this wave's LDS reads landed
        RAW_BARRIER();                   // all waves done with buf bi
        if (s + 2 < nsteps) stage(bi, (s + 2) * 32);
    }

    const float* isB = invSum + qblk * 64;
#pragma unroll
    for (int mt = 0; mt < 2; mt++)
#pragma unroll
        for (int nt = 0; nt < 4; nt++)
#pragma unroll
            for (int reg = 0; reg < 4; reg++) {
                int row = wm + mt * 16 + quad * 4 + reg;
                int col = n0 + wn + nt * 16 + c16;
                out[(long)(b * S + q0 + row) * D + col] = acc[mt][nt][reg] * isB[row];
            }
}

extern "C" void kernel_launch(void* const* d_in, const int* in_sizes, int n_in,
                              void* d_out, int out_size, void* d_ws, size_t ws_size,
                              hipStream_t stream) {
    const float* X  = (const float*)d_in[0];
    const float* Y  = (const float*)d_in[1];
    const float* Wq = (const float*)d_in[2];
    const float* Wk = (const float*)d_in[3];
    const float* Wv = (const float*)d_in[4];
    float* out = (float*)d_out;

    const long NTOK = 16384, D = 1024;
    // fp16 workspace. Aliases (all stream-ordered safe):
    //   Kh = Yh   (Yh dead after Q-projection)
    //   Pg,invSum over Xh (Xh dead after V-projection; qk_kernel runs after)
    char* p = (char*)d_ws;
    _Float16* Xh  = (_Float16*)p; p += NTOK * D * 2;   // 32 MB
    _Float16* Yh  = (_Float16*)p; p += NTOK * D * 2;   // 32 MB (reused as Kh)
    _Float16* Wqh = (_Float16*)p; p += D * D * 2;      //  2 MB (pre-scaled by 1/32)
    _Float16* Wkh = (_Float16*)p; p += D * D * 2;
    _Float16* Wvh = (_Float16*)p; p += D * D * 2;
    _Float16* Qh  = (_Float16*)p; p += NTOK * D * 2;   // 32 MB
    _Float16* Vt  = (_Float16*)p; p += NTOK * D * 2;   // 32 MB  [D][NTOK]
    _Float16* Kh  = Yh;
    _Float16* Pg  = Xh;                                // 256*64*576*2 = 18.9 MB
    float* invSum = (float*)(Xh + 256l * 64 * 576);    // 64 KB, still inside Xh

    const int nT = (int)(NTOK * D);                    // 16M elements each
    // X+Y in one launch; 3 weights (with Wq scale) in one launch
    cvt2_kernel<<<(2 * nT) / 2048, 256, 0, stream>>>(X, Xh, nT, Y, Yh);
    cvt3w_kernel<<<(3 * 1024 * 1024) / 2048, 256, 0, stream>>>(Wq, Wk, Wv, Wqh, Wkh, Wvh);

    // Q = Y Wq^T (scaled), K = X Wk^T, Vt = Wv X^T  (256^2 tiles, 8-phase)
    gemm_bt<<<dim3(1024 / 256, 16384 / 256), 512, 0, stream>>>(Yh, Wqh, Qh, 16384, 1024, 1024);
    gemm_bt<<<dim3(1024 / 256, 16384 / 256), 512, 0, stream>>>(Xh, Wkh, Kh, 16384, 1024, 1024);
    gemm_bt<<<dim3(16384 / 256, 1024 / 256), 512, 0, stream>>>(Wvh, Xh, Vt, 1024, 16384, 1024);

    qk_kernel<<<dim3(256), 512, 0, stream>>>(Qh, Kh, Pg, invSum);
    pv_kernel<<<dim3(4 * 256), 512, 0, stream>>>(Pg, invSum, Vt, out);
}